// Round 10
// baseline (338.766 us; speedup 1.0000x reference)
//
#include <hip/hip_runtime.h>
#include <hip/hip_cooperative_groups.h>
#include <stdint.h>

namespace cg = cooperative_groups;

// Problem constants
#define B_ 16
#define T_ 2048
#define D_ 256
#define QK_ 64
#define LOG2E 1.44269504088896340736f
#define NU 1024      // work units per phase
#define GRIDB 512    // cooperative grid (2 blocks/CU -- safe co-residency)

typedef _Float16 f16;
typedef _Float16 f16x2 __attribute__((ext_vector_type(2)));
typedef __fp16 fp16x2 __attribute__((ext_vector_type(2)));
typedef _Float16 f16x8 __attribute__((ext_vector_type(8)));
typedef float f32x16 __attribute__((ext_vector_type(16)));

__device__ __forceinline__ float fexp2(float x) {
#if __has_builtin(__builtin_amdgcn_exp2f)
    return __builtin_amdgcn_exp2f(x);
#else
    return exp2f(x);
#endif
}
__device__ __forceinline__ float flog2(float x) {
#if __has_builtin(__builtin_amdgcn_logf)
    return __builtin_amdgcn_logf(x);
#else
    return log2f(x);
#endif
}
__device__ __forceinline__ f16x2 cvt2(float a, float b) {
#if __has_builtin(__builtin_amdgcn_cvt_pkrtz)
    fp16x2 r = __builtin_amdgcn_cvt_pkrtz(a, b);
    return __builtin_bit_cast(f16x2, r);
#else
    f16x2 r; r[0] = (f16)a; r[1] = (f16)b; return r;
#endif
}
__device__ __forceinline__ f16x8 cvt8(const float* p) {
    union { f16x2 h2[4]; f16x8 h8; } u;
    const float4 a0 = *(const float4*)p;
    const float4 a1 = *(const float4*)(p + 4);
    u.h2[0] = cvt2(a0.x, a0.y); u.h2[1] = cvt2(a0.z, a0.w);
    u.h2[2] = cvt2(a1.x, a1.y); u.h2[3] = cvt2(a1.z, a1.w);
    return u.h8;
}

// Shared scratch: raw 16KB (xs / red) + aux 528 floats
struct SMem { char raw[16384]; float auxf[528]; };

// ---------------------------------------------------------------------------
// Frag-major layout (A and B operands of mfma_32x32x16_f16 share it; verified
// R2): [b][tile32][kc(4)][hi(2)][lo(32)][8]; lane l -> offset l*8, kc*512.
//   A: row=l&31, k=(l>>5)*8+j ; B: col=l&31, k=(l>>5)*8+j
//   C: col=l&31, row=(i&3)+8*(i>>2)+4*(l>>5)
// ---------------------------------------------------------------------------

// Phase P: projection unit u = b*64+tile (32 t-rows) -> qf, kf
__device__ __forceinline__ void phaseP(int u, int tid, SMem* sm,
    const float* __restrict__ x, const float* __restrict__ sl,
    const float* __restrict__ Wq, const float* __restrict__ bq,
    const float* __restrict__ Wk, const float* __restrict__ bk,
    f16* __restrict__ qf, f16* __restrict__ kf)
{
    f16* xs = (f16*)sm->raw;
    float* auxf = sm->auxf;
    const int wv = tid >> 6, l = tid & 63, lo = l & 31, hi = l >> 5;
    const int b = u >> 6, tile = u & 63, t0 = tile * 32;

    #pragma unroll
    for (int i = 0; i < 4; ++i) {
        const int f = i * 256 + tid;
        const int r = f >> 5, j = f & 31;
        const f16x8 h = cvt8(x + (size_t)(b * T_ + t0 + r) * D_ + j * 8);
        *(f16x8*)(xs + r * D_ + ((j ^ r) << 3)) = h;
    }
    if (tid < 32) {
        float s = sl[(size_t)b * T_ + t0 + tid];
        s = fminf(fmaxf(s, 0.f), 1.f);
        auxf[tid] = 0.125f * (1.f + s * s) * LOG2E;
    }
    __syncthreads();

    const int e = wv * 32 + lo;
    const float* wrow = ((e < 64) ? (Wq + (size_t)e * D_)
                                  : (Wk + (size_t)(e - 64) * D_)) + hi * 8;
    f32x16 acc;
    #pragma unroll
    for (int i = 0; i < 16; ++i) acc[i] = 0.f;
    #pragma unroll
    for (int ks = 0; ks < 16; ++ks) {
        const f16x8 a  = *(const f16x8*)(xs + lo * D_ + ((((ks << 1) + hi) ^ lo) << 3));
        const f16x8 bf = cvt8(wrow + ks * 16);
        acc = __builtin_amdgcn_mfma_f32_32x32x16_f16(a, bf, acc, 0, 0, 0);
    }
    const float bias = (e < 64) ? bq[e] : bk[e - 64];
    __syncthreads();                   // xs reads done -> reuse as hout
    f16* hout = xs;                    // [32 rows][128 e]
    #pragma unroll
    for (int i = 0; i < 16; ++i) {
        const int row = (i & 3) + 8 * (i >> 2) + 4 * hi;
        float v = acc[i] + bias;
        if (e >= 64) v *= auxf[row];
        hout[row * 128 + e] = (f16)v;
    }
    __syncthreads();
    const int kc2 = tid >> 6, hi2 = (tid >> 5) & 1, lo2 = tid & 31;
    const f16* srcq = hout + lo2 * 128 + kc2 * 16 + hi2 * 8;
    const size_t tb = ((size_t)b * 64 + tile) * 2048 + tid * 8;
    *(f16x8*)(qf + tb) = *(const f16x8*)srcq;
    *(f16x8*)(kf + tb) = *(const f16x8*)(srcq + 64);
    __syncthreads();                   // protect smem for next unit/phase
}

// Phase Z: unit u = b*64 + tIdx*4 + ckg: 128 t-rows x 512 s-chunk
__device__ __forceinline__ void phaseZ(int u, int tid, SMem* sm,
    const f16* __restrict__ qf, const f16* __restrict__ kf,
    const int* __restrict__ mask, float* __restrict__ zpart)
{
    float* red = (float*)sm->raw;      // [128][32]
    const int wv = tid >> 6, l = tid & 63, lo = l & 31, hi = l >> 5;
    const int b = u >> 6, rem = u & 63, tIdx = rem >> 2, ckg = rem & 3;

    const f16* abase = qf + ((size_t)b * 64 + tIdx * 4 + wv) * 2048 + l * 8;
    f16x8 a[4];
    #pragma unroll
    for (int kc = 0; kc < 4; ++kc) a[kc] = *(const f16x8*)(abase + kc * 512);

    float zp[16];
    #pragma unroll
    for (int i = 0; i < 16; ++i) zp[i] = 0.f;

    for (int g = 0; g < 16; ++g) {
        const int stile = ckg * 16 + g;
        const float mb = mask[b * T_ + stile * 32 + lo] ? 0.f : -1e9f;
        const f16* bbase = kf + ((size_t)b * 64 + stile) * 2048 + l * 8;
        f32x16 c;
        #pragma unroll
        for (int i = 0; i < 16; ++i) c[i] = mb;
        #pragma unroll
        for (int kc = 0; kc < 4; ++kc) {
            const f16x8 bf = *(const f16x8*)(bbase + kc * 512);
            c = __builtin_amdgcn_mfma_f32_32x32x16_f16(a[kc], bf, c, 0, 0, 0);
        }
        #pragma unroll
        for (int i = 0; i < 16; ++i) zp[i] += fexp2(c[i]);
    }
    #pragma unroll
    for (int i = 0; i < 16; ++i) {
        const int row = wv * 32 + (i & 3) + 8 * (i >> 2) + 4 * hi;
        const int col = (lo & 3) | ((((lo >> 2) ^ row) & 7) << 2);
        red[row * 32 + col] = zp[i];
    }
    __syncthreads();
    if (tid < 128) {
        float s = 0.f;
        #pragma unroll
        for (int c = 0; c < 8; ++c) {
            const float4 v = *(const float4*)(red + tid * 32 + (((c ^ tid) & 7) << 2));
            s += v.x + v.y + v.z + v.w;
        }
        zpart[(size_t)(b * 4 + ckg) * T_ + tIdx * 128 + tid] = s;
    }
    __syncthreads();
}

// Phase W: unit u = b*64 + sIdx*4 + tcg: 128 s-rows x 512 t-chunk
__device__ __forceinline__ void phaseW(int u, int tid, SMem* sm,
    const f16* __restrict__ qf, const f16* __restrict__ kf,
    const float* __restrict__ zpart, float* __restrict__ wpart)
{
    float* red = (float*)sm->raw;
    float* auxf = sm->auxf;
    const int wv = tid >> 6, l = tid & 63, lo = l & 31, hi = l >> 5;
    const int b = u >> 6, rem = u & 63, sIdx = rem >> 2, tcg = rem & 3;

    #pragma unroll
    for (int i = 0; i < 2; ++i) {      // lz for this unit's 512 t-cols
        const int tl = i * 256 + tid;
        const float* zb = zpart + (size_t)(b * 4) * T_ + tcg * 512 + tl;
        const float z = zb[0] + zb[T_] + zb[2 * T_] + zb[3 * T_];
        auxf[tl] = -flog2(z);
    }
    const f16* abase = kf + ((size_t)b * 64 + sIdx * 4 + wv) * 2048 + l * 8;
    f16x8 a[4];
    #pragma unroll
    for (int kc = 0; kc < 4; ++kc) a[kc] = *(const f16x8*)(abase + kc * 512);

    float wp[16];
    #pragma unroll
    for (int i = 0; i < 16; ++i) wp[i] = 0.f;
    __syncthreads();                   // auxf(lz) ready

    for (int g = 0; g < 16; ++g) {
        const int qtile = tcg * 16 + g;
        const float bias = auxf[g * 32 + lo];
        const f16* bbase = qf + ((size_t)b * 64 + qtile) * 2048 + l * 8;
        f32x16 c;
        #pragma unroll
        for (int i = 0; i < 16; ++i) c[i] = bias;
        #pragma unroll
        for (int kc = 0; kc < 4; ++kc) {
            const f16x8 bf = *(const f16x8*)(bbase + kc * 512);
            c = __builtin_amdgcn_mfma_f32_32x32x16_f16(a[kc], bf, c, 0, 0, 0);
        }
        #pragma unroll
        for (int i = 0; i < 16; ++i) wp[i] += fexp2(c[i]);
    }
    __syncthreads();                   // auxf reads done
    #pragma unroll
    for (int i = 0; i < 16; ++i) {
        const int row = wv * 32 + (i & 3) + 8 * (i >> 2) + 4 * hi;
        const int col = (lo & 3) | ((((lo >> 2) ^ row) & 7) << 2);
        red[row * 32 + col] = wp[i];
    }
    __syncthreads();
    if (tid < 128) {
        float s = 0.f;
        #pragma unroll
        for (int c = 0; c < 8; ++c) {
            const float4 v = *(const float4*)(red + tid * 32 + (((c ^ tid) & 7) << 2));
            s += v.x + v.y + v.z + v.w;
        }
        wpart[(size_t)(b * 4 + tcg) * T_ + sIdx * 128 + tid] = s;
    }
    __syncthreads();
}

// Phase Y: unit u = b*64+ch (32 s-rows): w -> ypart, swp
__device__ __forceinline__ void phaseY(int u, int tid, SMem* sm,
    const float* __restrict__ x, const float* __restrict__ wpart,
    const int* __restrict__ mask, float* __restrict__ ypart,
    float* __restrict__ swp)
{
    float* auxf = sm->auxf;
    const int b = u >> 6, ch = u & 63;
    if (tid < 32) {
        const int s = ch * 32 + tid;
        const float* wb = wpart + (size_t)(b * 4) * T_ + s;
        float v = wb[0] + wb[T_] + wb[2 * T_] + wb[3 * T_];
        v *= mask[b * T_ + s] ? (1.f / (float)T_) : 0.f;
        auxf[tid] = v;
        float sv = v;
        #pragma unroll
        for (int off = 1; off <= 16; off <<= 1) sv += __shfl_xor(sv, off);
        if (tid == 0) swp[b * 64 + ch] = sv;
    }
    __syncthreads();
    const float* xb = x + ((size_t)b * T_ + ch * 32) * D_;
    float acc = 0.f;
    #pragma unroll 8
    for (int s = 0; s < 32; ++s) acc += auxf[s] * xb[(size_t)s * D_ + tid];
    ypart[((size_t)b * 64 + ch) * D_ + tid] = acc;
    __syncthreads();
}

// Phase OUT: unit u = b
__device__ __forceinline__ void phaseOUT(int u, int tid, SMem* sm,
    const float* __restrict__ ypart, const float* __restrict__ swp,
    const float* __restrict__ Wv, const float* __restrict__ bv,
    float* __restrict__ out)
{
    float* auxf = sm->auxf;
    const int b = u;
    float yv = 0.f;
    #pragma unroll
    for (int ch = 0; ch < 64; ++ch) yv += ypart[((size_t)b * 64 + ch) * D_ + tid];
    auxf[tid] = yv;
    float s = (tid < 64) ? swp[b * 64 + tid] : 0.f;
    #pragma unroll
    for (int off = 1; off <= 32; off <<= 1) s += __shfl_xor(s, off);
    if (tid == 0) auxf[256] = s;
    __syncthreads();
    const float sw = auxf[256];
    const float4* wv4 = (const float4*)(Wv + (size_t)tid * D_);
    const float4* ys4 = (const float4*)auxf;
    float o = 0.f;
    #pragma unroll
    for (int i = 0; i < D_ / 4; ++i) {
        const float4 a = wv4[i];
        const float4 y = ys4[i];
        o += a.x * y.x + a.y * y.y + a.z * y.z + a.w * y.w;
    }
    out[(size_t)b * D_ + tid] = o + bv[tid] * sw;
}

// ---------------------------------------------------------------------------
// Fused cooperative kernel: 512 blocks x 256 thr, grid-strided units.
// ---------------------------------------------------------------------------
__global__ __launch_bounds__(256, 4) void fused(
    const float* __restrict__ x, const float* __restrict__ sl,
    const int* __restrict__ mask,
    const float* __restrict__ Wq, const float* __restrict__ bq,
    const float* __restrict__ Wk, const float* __restrict__ bk,
    const float* __restrict__ Wv, const float* __restrict__ bv,
    float* __restrict__ out,
    f16* __restrict__ qf, f16* __restrict__ kf,
    float* __restrict__ zpart, float* __restrict__ wpart,
    float* __restrict__ swp, float* __restrict__ ypart)
{
    __shared__ SMem sm;
    const int tid = threadIdx.x;
    cg::grid_group grid = cg::this_grid();

    for (int u = blockIdx.x; u < NU; u += GRIDB)
        phaseP(u, tid, &sm, x, sl, Wq, bq, Wk, bk, qf, kf);
    grid.sync();
    for (int u = blockIdx.x; u < NU; u += GRIDB)
        phaseZ(u, tid, &sm, qf, kf, mask, zpart);
    grid.sync();
    for (int u = blockIdx.x; u < NU; u += GRIDB)
        phaseW(u, tid, &sm, qf, kf, zpart, wpart);
    grid.sync();
    for (int u = blockIdx.x; u < NU; u += GRIDB)
        phaseY(u, tid, &sm, x, wpart, mask, ypart, swp);
    grid.sync();
    for (int u = blockIdx.x; u < B_; u += GRIDB)
        phaseOUT(u, tid, &sm, ypart, swp, Wv, bv, out);
}

// ---------------------------------------------------------------------------
// Discrete fallback kernels (same device functions, no grid sync needed).
// ---------------------------------------------------------------------------
__global__ __launch_bounds__(256, 4) void kP(
    const float* __restrict__ x, const float* __restrict__ sl,
    const float* __restrict__ Wq, const float* __restrict__ bq,
    const float* __restrict__ Wk, const float* __restrict__ bk,
    f16* __restrict__ qf, f16* __restrict__ kf)
{
    __shared__ SMem sm;
    phaseP(blockIdx.x, threadIdx.x, &sm, x, sl, Wq, bq, Wk, bk, qf, kf);
}
__global__ __launch_bounds__(256, 4) void kZ(
    const f16* __restrict__ qf, const f16* __restrict__ kf,
    const int* __restrict__ mask, float* __restrict__ zpart)
{
    __shared__ SMem sm;
    phaseZ(blockIdx.x, threadIdx.x, &sm, qf, kf, mask, zpart);
}
__global__ __launch_bounds__(256, 4) void kW(
    const f16* __restrict__ qf, const f16* __restrict__ kf,
    const float* __restrict__ zpart, float* __restrict__ wpart)
{
    __shared__ SMem sm;
    phaseW(blockIdx.x, threadIdx.x, &sm, qf, kf, zpart, wpart);
}
__global__ __launch_bounds__(256, 4) void kY(
    const float* __restrict__ x, const float* __restrict__ wpart,
    const int* __restrict__ mask, float* __restrict__ ypart,
    float* __restrict__ swp)
{
    __shared__ SMem sm;
    phaseY(blockIdx.x, threadIdx.x, &sm, x, wpart, mask, ypart, swp);
}
__global__ __launch_bounds__(256, 4) void kOUT(
    const float* __restrict__ ypart, const float* __restrict__ swp,
    const float* __restrict__ Wv, const float* __restrict__ bv,
    float* __restrict__ out)
{
    __shared__ SMem sm;
    phaseOUT(blockIdx.x, threadIdx.x, &sm, ypart, swp, Wv, bv, out);
}

// ---------------------------------------------------------------------------
extern "C" void kernel_launch(void* const* d_in, const int* in_sizes, int n_in,
                              void* d_out, int out_size, void* d_ws, size_t ws_size,
                              hipStream_t stream)
{
    const float* x    = (const float*)d_in[0];
    const float* sl   = (const float*)d_in[1];
    const int*   mask = (const int*)d_in[2];
    const float* Wq   = (const float*)d_in[3];
    const float* bq   = (const float*)d_in[4];
    const float* Wk   = (const float*)d_in[5];
    const float* bk   = (const float*)d_in[6];
    const float* Wv   = (const float*)d_in[7];
    const float* bv   = (const float*)d_in[8];
    float* out = (float*)d_out;

    // workspace: qf 4MB | kf 4MB | zpart 512KB | wpart 512KB | swp 4KB | yp 1MB
    f16*   qf    = (f16*)d_ws;
    f16*   kf    = qf + (size_t)B_ * T_ * QK_;
    float* zpart = (float*)(kf + (size_t)B_ * T_ * QK_);
    float* wpart = zpart + (size_t)B_ * 4 * T_;
    float* swp   = wpart + (size_t)B_ * 4 * T_;
    float* yp    = swp + B_ * 64;

    // Capture-safe queries (no stream ops) -> deterministic path choice.
    int dev = 0, coop = 0, nCU = 0, maxBlk = 0;
    hipGetDevice(&dev);
    hipDeviceGetAttribute(&coop, hipDeviceAttributeCooperativeLaunch, dev);
    hipDeviceGetAttribute(&nCU, hipDeviceAttributeMultiprocessorCount, dev);
    hipOccupancyMaxActiveBlocksPerMultiprocessor(&maxBlk, fused, 256, 0);

    bool launched = false;
    if (coop && (long)maxBlk * nCU >= GRIDB) {
        void* args[] = {
            (void*)&x, (void*)&sl, (void*)&mask, (void*)&Wq, (void*)&bq,
            (void*)&Wk, (void*)&bk, (void*)&Wv, (void*)&bv, (void*)&out,
            (void*)&qf, (void*)&kf, (void*)&zpart, (void*)&wpart,
            (void*)&swp, (void*)&yp
        };
        launched = hipLaunchCooperativeKernel((void*)fused, dim3(GRIDB), dim3(256),
                                              args, 0, stream) == hipSuccess;
    }
    if (!launched) {
        kP  <<<dim3(NU), 256, 0, stream>>>(x, sl, Wq, bq, Wk, bk, qf, kf);
        kZ  <<<dim3(NU), 256, 0, stream>>>(qf, kf, mask, zpart);
        kW  <<<dim3(NU), 256, 0, stream>>>(qf, kf, zpart, wpart);
        kY  <<<dim3(NU), 256, 0, stream>>>(x, wpart, mask, yp, swp);
        kOUT<<<dim3(B_), 256, 0, stream>>>(yp, swp, Wv, bv, out);
    }
}

// Round 11
// 93.468 us; speedup vs baseline: 3.6244x; 3.6244x over previous
//
#include <hip/hip_runtime.h>
#include <stdint.h>

// Problem constants
#define B_ 16
#define T_ 2048
#define D_ 256
#define QK_ 64
#define LOG2E 1.44269504088896340736f
#define NCH 8      // s/t chunks per batch in z/w passes (chunk = 256)

typedef _Float16 f16;
typedef _Float16 f16x2 __attribute__((ext_vector_type(2)));
typedef __fp16 fp16x2 __attribute__((ext_vector_type(2)));
typedef _Float16 f16x8 __attribute__((ext_vector_type(8)));
typedef float f32x16 __attribute__((ext_vector_type(16)));

__device__ __forceinline__ float fexp2(float x) {
#if __has_builtin(__builtin_amdgcn_exp2f)
    return __builtin_amdgcn_exp2f(x);
#else
    return exp2f(x);
#endif
}
__device__ __forceinline__ float flog2(float x) {
#if __has_builtin(__builtin_amdgcn_logf)
    return __builtin_amdgcn_logf(x);
#else
    return log2f(x);
#endif
}
__device__ __forceinline__ f16x2 cvt2(float a, float b) {
#if __has_builtin(__builtin_amdgcn_cvt_pkrtz)
    fp16x2 r = __builtin_amdgcn_cvt_pkrtz(a, b);
    return __builtin_bit_cast(f16x2, r);
#else
    f16x2 r; r[0] = (f16)a; r[1] = (f16)b; return r;
#endif
}
__device__ __forceinline__ f16x8 cvt8(const float* p) {
    union { f16x2 h2[4]; f16x8 h8; } u;
    const float4 a0 = *(const float4*)p;
    const float4 a1 = *(const float4*)(p + 4);
    u.h2[0] = cvt2(a0.x, a0.y); u.h2[1] = cvt2(a0.z, a0.w);
    u.h2[2] = cvt2(a1.x, a1.y); u.h2[3] = cvt2(a1.z, a1.w);
    return u.h8;
}

// ---------------------------------------------------------------------------
// Frag-major layout (A and B operands of mfma_32x32x16_f16 share it; verified
// R2): [b][tile32][kc(4)][hi(2)][lo(32)][8]; lane l -> byte l*16, k-chunk kc
// at +kc*1KB. One wave operand-load = contiguous 1KB.
//   A: row=l&31, k=(l>>5)*8+j ; B: col=l&31, k=(l>>5)*8+j
//   C: col=l&31, row=(i&3)+8*(i>>2)+4*(l>>5)
// ---------------------------------------------------------------------------

// Kernel P: projection. unit = (b, tile of 32 t-rows) -> qf, kf (frag-major).
// x staged in LDS f32->f16 (32-slot XOR swizzle); W cvt'd in-loop (L2-hot).
__global__ __launch_bounds__(256, 4) void kP(
    const float* __restrict__ x, const float* __restrict__ sl,
    const float* __restrict__ Wq, const float* __restrict__ bq,
    const float* __restrict__ Wk, const float* __restrict__ bk,
    f16* __restrict__ qf, f16* __restrict__ kf)
{
    __shared__ __align__(16) f16 xs[32 * D_];   // 16 KB; reused as hout[32][128]
    __shared__ float ksc[32];
    const int tid = threadIdx.x;
    const int wv = tid >> 6, l = tid & 63, lo = l & 31, hi = l >> 5;
    const int b = blockIdx.y, tile = blockIdx.x, t0 = tile * 32;

    #pragma unroll
    for (int i = 0; i < 4; ++i) {
        const int f = i * 256 + tid;
        const int r = f >> 5, j = f & 31;
        const f16x8 h = cvt8(x + (size_t)(b * T_ + t0 + r) * D_ + j * 8);
        *(f16x8*)(xs + r * D_ + ((j ^ r) << 3)) = h;
    }
    if (tid < 32) {
        float s = sl[(size_t)b * T_ + t0 + tid];
        s = fminf(fmaxf(s, 0.f), 1.f);
        ksc[tid] = 0.125f * (1.f + s * s) * LOG2E;
    }
    __syncthreads();

    const int e = wv * 32 + lo;
    const float* wrow = ((e < 64) ? (Wq + (size_t)e * D_)
                                  : (Wk + (size_t)(e - 64) * D_)) + hi * 8;
    f32x16 acc;
    #pragma unroll
    for (int i = 0; i < 16; ++i) acc[i] = 0.f;
    #pragma unroll
    for (int ks = 0; ks < 16; ++ks) {
        const f16x8 a  = *(const f16x8*)(xs + lo * D_ + ((((ks << 1) + hi) ^ lo) << 3));
        const f16x8 bf = cvt8(wrow + ks * 16);
        acc = __builtin_amdgcn_mfma_f32_32x32x16_f16(a, bf, acc, 0, 0, 0);
    }
    const float bias = (e < 64) ? bq[e] : bk[e - 64];
    __syncthreads();                   // xs reads done -> reuse as hout
    f16* hout = xs;                    // [32 rows][128 e]
    #pragma unroll
    for (int i = 0; i < 16; ++i) {
        const int row = (i & 3) + 8 * (i >> 2) + 4 * hi;
        float v = acc[i] + bias;
        if (e >= 64) v *= ksc[row];
        hout[row * 128 + e] = (f16)v;
    }
    __syncthreads();
    // frag-major stores: chunk tid = [kc][hi][lo]; one q + one k2 16B chunk
    const int kc2 = tid >> 6, hi2 = (tid >> 5) & 1, lo2 = tid & 31;
    const f16* srcq = hout + lo2 * 128 + kc2 * 16 + hi2 * 8;
    const size_t tb = ((size_t)b * 64 + tile) * 2048 + tid * 8;
    *(f16x8*)(qf + tb) = *(const f16x8*)srcq;
    *(f16x8*)(kf + tb) = *(const f16x8*)(srcq + 64);
}

// Kernel Z: zpart[(b*8+ckg)][t] = sum_{s in 256-chunk ckg} 2^(S+maskbias)
// Barrier-free main loop; A and B frag-major coalesced; LDS only for the
// final transpose reduction. grid (128, B) = 2048 blocks -> 8 blocks/CU.
__global__ __launch_bounds__(256, 4) void kZ(
    const f16* __restrict__ qf, const f16* __restrict__ kf,
    const int* __restrict__ mask, float* __restrict__ zpart)
{
    __shared__ __align__(16) float red[128 * 32];   // 16 KB
    const int tid = threadIdx.x;
    const int wv = tid >> 6, l = tid & 63, lo = l & 31, hi = l >> 5;
    const int b = blockIdx.y;
    const int tIdx = blockIdx.x >> 3, ckg = blockIdx.x & 7;

    const f16* abase = qf + ((size_t)b * 64 + tIdx * 4 + wv) * 2048 + l * 8;
    f16x8 a[4];
    #pragma unroll
    for (int kc = 0; kc < 4; ++kc) a[kc] = *(const f16x8*)(abase + kc * 512);

    float zp[16];
    #pragma unroll
    for (int i = 0; i < 16; ++i) zp[i] = 0.f;

    #pragma unroll
    for (int g = 0; g < 8; ++g) {
        const int stile = ckg * 8 + g;
        const float mb = mask[b * T_ + stile * 32 + lo] ? 0.f : -1e9f;
        const f16* bbase = kf + ((size_t)b * 64 + stile) * 2048 + l * 8;
        f32x16 c;
        #pragma unroll
        for (int i = 0; i < 16; ++i) c[i] = mb;
        #pragma unroll
        for (int kc = 0; kc < 4; ++kc) {
            const f16x8 bf = *(const f16x8*)(bbase + kc * 512);
            c = __builtin_amdgcn_mfma_f32_32x32x16_f16(a[kc], bf, c, 0, 0, 0);
        }
        #pragma unroll
        for (int i = 0; i < 16; ++i) zp[i] += fexp2(c[i]);
    }
    // LDS-transpose reduction over the 32 s-lanes
    #pragma unroll
    for (int i = 0; i < 16; ++i) {
        const int row = wv * 32 + (i & 3) + 8 * (i >> 2) + 4 * hi;
        const int col = (lo & 3) | ((((lo >> 2) ^ row) & 7) << 2);
        red[row * 32 + col] = zp[i];
    }
    __syncthreads();
    if (tid < 128) {
        float s = 0.f;
        #pragma unroll
        for (int c = 0; c < 8; ++c) {
            const float4 v = *(const float4*)(red + tid * 32 + (((c ^ tid) & 7) << 2));
            s += v.x + v.y + v.z + v.w;
        }
        zpart[(size_t)(b * NCH + ckg) * T_ + tIdx * 128 + tid] = s;
    }
}

// Kernel W: wpart[(b*8+tcg)][s] = sum_{t in 256-chunk tcg} 2^(S+lz[t]),
//   lz[t] = -log2(sum_ck zpart[ck][t]).  Mirror of kZ.
__global__ __launch_bounds__(256, 4) void kW(
    const f16* __restrict__ qf, const f16* __restrict__ kf,
    const float* __restrict__ zpart, float* __restrict__ wpart)
{
    __shared__ __align__(16) float red[128 * 32];   // 16 KB
    __shared__ float lz_s[256];
    const int tid = threadIdx.x;
    const int wv = tid >> 6, l = tid & 63, lo = l & 31, hi = l >> 5;
    const int b = blockIdx.y;
    const int sIdx = blockIdx.x >> 3, tcg = blockIdx.x & 7;

    {   // lz for this block's 256 t-cols (coalesced)
        const float* zb = zpart + (size_t)(b * NCH) * T_ + tcg * 256 + tid;
        float z = 0.f;
        #pragma unroll
        for (int ck = 0; ck < NCH; ++ck) z += zb[(size_t)ck * T_];
        lz_s[tid] = -flog2(z);
    }
    const f16* abase = kf + ((size_t)b * 64 + sIdx * 4 + wv) * 2048 + l * 8;
    f16x8 a[4];
    #pragma unroll
    for (int kc = 0; kc < 4; ++kc) a[kc] = *(const f16x8*)(abase + kc * 512);

    float wp[16];
    #pragma unroll
    for (int i = 0; i < 16; ++i) wp[i] = 0.f;
    __syncthreads();   // lz ready

    #pragma unroll
    for (int g = 0; g < 8; ++g) {
        const int qtile = tcg * 8 + g;
        const float bias = lz_s[g * 32 + lo];
        const f16* bbase = qf + ((size_t)b * 64 + qtile) * 2048 + l * 8;
        f32x16 c;
        #pragma unroll
        for (int i = 0; i < 16; ++i) c[i] = bias;
        #pragma unroll
        for (int kc = 0; kc < 4; ++kc) {
            const f16x8 bf = *(const f16x8*)(bbase + kc * 512);
            c = __builtin_amdgcn_mfma_f32_32x32x16_f16(a[kc], bf, c, 0, 0, 0);
        }
        #pragma unroll
        for (int i = 0; i < 16; ++i) wp[i] += fexp2(c[i]);
    }
    #pragma unroll
    for (int i = 0; i < 16; ++i) {
        const int row = wv * 32 + (i & 3) + 8 * (i >> 2) + 4 * hi;
        const int col = (lo & 3) | ((((lo >> 2) ^ row) & 7) << 2);
        red[row * 32 + col] = wp[i];
    }
    __syncthreads();
    if (tid < 128) {
        float s = 0.f;
        #pragma unroll
        for (int c = 0; c < 8; ++c) {
            const float4 v = *(const float4*)(red + tid * 32 + (((c ^ tid) & 7) << 2));
            s += v.x + v.y + v.z + v.w;
        }
        wpart[(size_t)(b * NCH + tcg) * T_ + sIdx * 128 + tid] = s;
    }
}

// Kernel Y: per 32-row chunk: w[s] = mask[s]/T * sum_ck wpart[ck][s];
//   ypart[b][ch][d] = sum_s w[s]*x[b,s,d];  swp[b][ch] = sum_s w[s]
__global__ __launch_bounds__(256, 4) void kY(
    const float* __restrict__ x, const float* __restrict__ wpart,
    const int* __restrict__ mask, float* __restrict__ ypart,
    float* __restrict__ swp)
{
    __shared__ float wloc[32];
    const int b  = blockIdx.y;
    const int ch = blockIdx.x;
    const int tid = threadIdx.x;

    if (tid < 32) {
        const int s = ch * 32 + tid;
        const float* wb = wpart + (size_t)(b * NCH) * T_ + s;
        float v = 0.f;
        #pragma unroll
        for (int ck = 0; ck < NCH; ++ck) v += wb[(size_t)ck * T_];
        v *= mask[b * T_ + s] ? (1.f / (float)T_) : 0.f;
        wloc[tid] = v;
        float sv = v;
        #pragma unroll
        for (int off = 1; off <= 16; off <<= 1) sv += __shfl_xor(sv, off);
        if (tid == 0) swp[b * 64 + ch] = sv;
    }
    __syncthreads();
    const float* xb = x + ((size_t)b * T_ + ch * 32) * D_;
    float acc = 0.f;
    #pragma unroll 8
    for (int s = 0; s < 32; ++s) acc += wloc[s] * xb[(size_t)s * D_ + tid];
    ypart[((size_t)b * 64 + ch) * D_ + tid] = acc;
}

// Kernel OUT: out[b][e] = sum_d y[b,d]*Wv[e,d] + bv[e]*sum_s w[b,s]
__global__ __launch_bounds__(256, 4) void kOUT(
    const float* __restrict__ ypart, const float* __restrict__ swp,
    const float* __restrict__ Wv, const float* __restrict__ bv,
    float* __restrict__ out)
{
    __shared__ __align__(16) float ys[D_];
    __shared__ float sw0;
    const int b   = blockIdx.x;
    const int tid = threadIdx.x;

    float yv = 0.f;
    #pragma unroll
    for (int ch = 0; ch < 64; ++ch) yv += ypart[((size_t)b * 64 + ch) * D_ + tid];
    ys[tid] = yv;
    float s = (tid < 64) ? swp[b * 64 + tid] : 0.f;
    #pragma unroll
    for (int off = 1; off <= 32; off <<= 1) s += __shfl_xor(s, off);
    if (tid == 0) sw0 = s;
    __syncthreads();
    const float sw = sw0;
    const float4* wv4 = (const float4*)(Wv + (size_t)tid * D_);
    const float4* ys4 = (const float4*)ys;
    float o = 0.f;
    #pragma unroll
    for (int i = 0; i < D_ / 4; ++i) {
        const float4 a = wv4[i];
        const float4 y = ys4[i];
        o += a.x * y.x + a.y * y.y + a.z * y.z + a.w * y.w;
    }
    out[(size_t)b * D_ + tid] = o + bv[tid] * sw;
}

// ---------------------------------------------------------------------------
extern "C" void kernel_launch(void* const* d_in, const int* in_sizes, int n_in,
                              void* d_out, int out_size, void* d_ws, size_t ws_size,
                              hipStream_t stream)
{
    const float* x    = (const float*)d_in[0];
    const float* sl   = (const float*)d_in[1];
    const int*   mask = (const int*)d_in[2];
    const float* Wq   = (const float*)d_in[3];
    const float* bq   = (const float*)d_in[4];
    const float* Wk   = (const float*)d_in[5];
    const float* bk   = (const float*)d_in[6];
    const float* Wv   = (const float*)d_in[7];
    const float* bv   = (const float*)d_in[8];
    float* out = (float*)d_out;

    // workspace: qf 4MB | kf 4MB | zpart 1MB | wpart 1MB | swp 4KB | yp 1MB
    f16*   qf    = (f16*)d_ws;
    f16*   kf    = qf + (size_t)B_ * T_ * QK_;
    float* zpart = (float*)(kf + (size_t)B_ * T_ * QK_);
    float* wpart = zpart + (size_t)B_ * NCH * T_;
    float* swp   = wpart + (size_t)B_ * NCH * T_;
    float* yp    = swp + B_ * 64;

    kP  <<<dim3(64, B_), 256, 0, stream>>>(x, sl, Wq, bq, Wk, bk, qf, kf);
    kZ  <<<dim3(128, B_), 256, 0, stream>>>(qf, kf, mask, zpart);
    kW  <<<dim3(128, B_), 256, 0, stream>>>(qf, kf, zpart, wpart);
    kY  <<<dim3(64, B_), 256, 0, stream>>>(x, wpart, mask, yp, swp);
    kOUT<<<dim3(B_), 256, 0, stream>>>(yp, swp, Wv, bv, out);
}

// Round 12
// 82.739 us; speedup vs baseline: 4.0944x; 1.1297x over previous
//
#include <hip/hip_runtime.h>
#include <stdint.h>

// Problem constants
#define B_ 16
#define T_ 2048
#define D_ 256
#define QK_ 64
#define LOG2E 1.44269504088896340736f
#define NCH 8      // t/s chunks per batch in z/w passes

typedef _Float16 f16;
typedef _Float16 f16x2 __attribute__((ext_vector_type(2)));
typedef __fp16 fp16x2 __attribute__((ext_vector_type(2)));
typedef _Float16 f16x8 __attribute__((ext_vector_type(8)));
typedef float f32x16 __attribute__((ext_vector_type(16)));

__device__ __forceinline__ float fexp2(float x) {
#if __has_builtin(__builtin_amdgcn_exp2f)
    return __builtin_amdgcn_exp2f(x);
#else
    return exp2f(x);
#endif
}
__device__ __forceinline__ float flog2(float x) {
#if __has_builtin(__builtin_amdgcn_logf)
    return __builtin_amdgcn_logf(x);
#else
    return log2f(x);
#endif
}
__device__ __forceinline__ f16x2 cvt2(float a, float b) {
#if __has_builtin(__builtin_amdgcn_cvt_pkrtz)
    fp16x2 r = __builtin_amdgcn_cvt_pkrtz(a, b);
    return __builtin_bit_cast(f16x2, r);
#else
    f16x2 r; r[0] = (f16)a; r[1] = (f16)b; return r;
#endif
}
__device__ __forceinline__ f16x8 cvt8(const float* p) {
    union { f16x2 h2[4]; f16x8 h8; } u;
    const float4 a0 = *(const float4*)p;
    const float4 a1 = *(const float4*)(p + 4);
    u.h2[0] = cvt2(a0.x, a0.y); u.h2[1] = cvt2(a0.z, a0.w);
    u.h2[2] = cvt2(a1.x, a1.y); u.h2[3] = cvt2(a1.z, a1.w);
    return u.h8;
}

// ---------------------------------------------------------------------------
// Frag-major layout (A and B operands of mfma_32x32x16_f16 share it; verified
// R2): [b][tile32][kc(4)][hi(2)][lo(32)][8]; element offset within a 4KB tile
// = kc*512 + hi*256 + lo*8. One wave operand-load = contiguous 1KB.
//   A: row=l&31, k=(l>>5)*8+j ; B: col=l&31, k=(l>>5)*8+j
//   C: col=l&31, row=(i&3)+8*(i>>2)+4*(l>>5)
// ---------------------------------------------------------------------------

// Kernel P: projection -> qf, kf (frag-major). Block (tile,b): 32 t-rows.
// Block tile==0 additionally builds the mask compaction (sidx/inv/Nv) for b.
__global__ __launch_bounds__(256, 4) void kP(
    const float* __restrict__ x, const float* __restrict__ sl,
    const int* __restrict__ mask,
    const float* __restrict__ Wq, const float* __restrict__ bq,
    const float* __restrict__ Wk, const float* __restrict__ bk,
    f16* __restrict__ qf, f16* __restrict__ kf,
    int* __restrict__ sidx, int* __restrict__ inv, int* __restrict__ nv)
{
    __shared__ __align__(16) f16 xs[32 * D_];   // 16 KB; reused as hout[32][128]
    __shared__ float ksc[32];
    __shared__ int wtot[4];
    const int tid = threadIdx.x;
    const int wv = tid >> 6, l = tid & 63, lo = l & 31, hi = l >> 5;
    const int b = blockIdx.y, tile = blockIdx.x, t0 = tile * 32;

    #pragma unroll
    for (int i = 0; i < 4; ++i) {
        const int f = i * 256 + tid;
        const int r = f >> 5, j = f & 31;
        const f16x8 h = cvt8(x + (size_t)(b * T_ + t0 + r) * D_ + j * 8);
        *(f16x8*)(xs + r * D_ + ((j ^ r) << 3)) = h;
    }
    if (tid < 32) {
        float s = sl[(size_t)b * T_ + t0 + tid];
        s = fminf(fmaxf(s, 0.f), 1.f);
        ksc[tid] = 0.125f * (1.f + s * s) * LOG2E;
    }
    __syncthreads();

    const int e = wv * 32 + lo;
    const float* wrow = ((e < 64) ? (Wq + (size_t)e * D_)
                                  : (Wk + (size_t)(e - 64) * D_)) + hi * 8;
    f32x16 acc;
    #pragma unroll
    for (int i = 0; i < 16; ++i) acc[i] = 0.f;
    #pragma unroll
    for (int ks = 0; ks < 16; ++ks) {
        const f16x8 a  = *(const f16x8*)(xs + lo * D_ + ((((ks << 1) + hi) ^ lo) << 3));
        const f16x8 bf = cvt8(wrow + ks * 16);
        acc = __builtin_amdgcn_mfma_f32_32x32x16_f16(a, bf, acc, 0, 0, 0);
    }
    const float bias = (e < 64) ? bq[e] : bk[e - 64];
    __syncthreads();                   // xs reads done -> reuse as hout
    f16* hout = xs;                    // [32 rows][128 e]
    #pragma unroll
    for (int i = 0; i < 16; ++i) {
        const int row = (i & 3) + 8 * (i >> 2) + 4 * hi;
        float v = acc[i] + bias;
        if (e >= 64) v *= ksc[row];
        hout[row * 128 + e] = (f16)v;
    }
    __syncthreads();
    // frag-major stores: chunk tid = [kc][hi][lo]
    const int kc2 = tid >> 6, hi2 = (tid >> 5) & 1, lo2 = tid & 31;
    const f16* srcq = hout + lo2 * 128 + kc2 * 16 + hi2 * 8;
    const size_t tb = ((size_t)b * 64 + tile) * 2048 + tid * 8;
    *(f16x8*)(qf + tb) = *(const f16x8*)srcq;
    *(f16x8*)(kf + tb) = *(const f16x8*)(srcq + 64);

    // ---- mask compaction for batch b (block tile==0 only) ----
    if (tile == 0) {
        int bits = 0, c = 0;
        #pragma unroll
        for (int i = 0; i < 8; ++i) {
            const int m = mask[b * T_ + tid * 8 + i] ? 1 : 0;
            bits |= m << i; c += m;
        }
        int cs = c;   // inclusive scan within wave
        #pragma unroll
        for (int off = 1; off < 64; off <<= 1) {
            const int v = __shfl_up(cs, off);
            if (l >= off) cs += v;
        }
        if (l == 63) wtot[wv] = cs;
        __syncthreads();
        int pos = cs - c;   // exclusive prefix
        #pragma unroll
        for (int w = 0; w < 4; ++w) if (w < wv) pos += wtot[w];
        #pragma unroll
        for (int i = 0; i < 8; ++i)
            if ((bits >> i) & 1) {
                sidx[b * T_ + pos] = tid * 8 + i;
                inv[b * T_ + tid * 8 + i] = pos;
                ++pos;
            }
        if (tid == 255) nv[b] = pos;
    }
}

// Kernel G: gather kf fragments of VALID rows into dense tiles kfc.
// grid (64, B); block = one compact tile; thread = one 16B chunk.
__global__ __launch_bounds__(256, 4) void kG(
    const f16* __restrict__ kf, const int* __restrict__ sidx,
    const int* __restrict__ nv, f16* __restrict__ kfc)
{
    const int b = blockIdx.y, tile = blockIdx.x;
    const int Nv = nv[b];
    if (tile * 32 >= Nv) return;
    const int tid = threadIdx.x;
    const int kc = tid >> 6, hi = (tid >> 5) & 1, lo = tid & 31;
    const int pos = tile * 32 + lo;
    const int r = (pos < Nv) ? sidx[b * T_ + pos] : 0;   // pad with row 0 (finite)
    const f16* src = kf + ((size_t)b * 64 + (r >> 5)) * 2048
                        + kc * 512 + hi * 256 + (r & 31) * 8;
    *(f16x8*)(kfc + ((size_t)b * 64 + tile) * 2048 + tid * 8) = *(const f16x8*)src;
}

// Kernel Z: zpart[(b*8+ckg)][t] = sum over this ckg's VALID s-tiles of
//   2^(S2[t,s] + padbias). Only ~Nv/32 tiles exist -> exp2/MFMA halved.
__global__ __launch_bounds__(256, 4) void kZ(
    const f16* __restrict__ qf, const f16* __restrict__ kfc,
    const int* __restrict__ nv, float* __restrict__ zpart)
{
    __shared__ __align__(16) float red[128 * 32];   // 16 KB
    const int tid = threadIdx.x;
    const int wv = tid >> 6, l = tid & 63, lo = l & 31, hi = l >> 5;
    const int b = blockIdx.y;
    const int tIdx = blockIdx.x >> 3, ckg = blockIdx.x & 7;
    const int Nv = nv[b];
    const int ntiles = (Nv + 31) >> 5;

    const f16* abase = qf + ((size_t)b * 64 + tIdx * 4 + wv) * 2048 + l * 8;
    f16x8 a[4];
    #pragma unroll
    for (int kc = 0; kc < 4; ++kc) a[kc] = *(const f16x8*)(abase + kc * 512);

    float zp[16];
    #pragma unroll
    for (int i = 0; i < 16; ++i) zp[i] = 0.f;

    for (int g = ckg; g < ntiles; g += 8) {
        const float mb = (g * 32 + lo < Nv) ? 0.f : -1e9f;   // pad bias
        const f16* bbase = kfc + ((size_t)b * 64 + g) * 2048 + l * 8;
        f32x16 c;
        #pragma unroll
        for (int i = 0; i < 16; ++i) c[i] = mb;
        #pragma unroll
        for (int kc = 0; kc < 4; ++kc) {
            const f16x8 bf = *(const f16x8*)(bbase + kc * 512);
            c = __builtin_amdgcn_mfma_f32_32x32x16_f16(a[kc], bf, c, 0, 0, 0);
        }
        #pragma unroll
        for (int i = 0; i < 16; ++i) zp[i] += fexp2(c[i]);
    }
    // LDS-transpose reduction over the 32 s-lanes
    #pragma unroll
    for (int i = 0; i < 16; ++i) {
        const int row = wv * 32 + (i & 3) + 8 * (i >> 2) + 4 * hi;
        const int col = (lo & 3) | ((((lo >> 2) ^ row) & 7) << 2);
        red[row * 32 + col] = zp[i];
    }
    __syncthreads();
    if (tid < 128) {
        float s = 0.f;
        #pragma unroll
        for (int c = 0; c < 8; ++c) {
            const float4 v = *(const float4*)(red + tid * 32 + (((c ^ tid) & 7) << 2));
            s += v.x + v.y + v.z + v.w;
        }
        zpart[(size_t)(b * NCH + ckg) * T_ + tIdx * 128 + tid] = s;
    }
}

// Kernel W: wpart[(b*8+tcg)][j] (compact j) = sum_{t in 256-chunk tcg}
//   2^(S2[t,s_j] + lz[t]),  lz[t] = -log2(sum_ck zpart[ck][t]).
// Blocks with sIdx*128 >= Nv exit -> ~half the blocks do work.
__global__ __launch_bounds__(256, 4) void kW(
    const f16* __restrict__ qf, const f16* __restrict__ kfc,
    const int* __restrict__ nv, const float* __restrict__ zpart,
    float* __restrict__ wpart)
{
    __shared__ __align__(16) float red[128 * 32];   // 16 KB
    __shared__ float lz_s[256];
    const int b = blockIdx.y;
    const int sIdx = blockIdx.x >> 3, tcg = blockIdx.x & 7;
    const int Nv = nv[b];
    if (sIdx * 128 >= Nv) return;
    const int tid = threadIdx.x;
    const int wv = tid >> 6, l = tid & 63, lo = l & 31, hi = l >> 5;

    {   // lz for this block's 256 t-cols (coalesced)
        const float* zb = zpart + (size_t)(b * NCH) * T_ + tcg * 256 + tid;
        float z = 0.f;
        #pragma unroll
        for (int ck = 0; ck < NCH; ++ck) z += zb[(size_t)ck * T_];
        lz_s[tid] = -flog2(z);
    }
    const f16* abase = kfc + ((size_t)b * 64 + sIdx * 4 + wv) * 2048 + l * 8;
    f16x8 a[4];
    #pragma unroll
    for (int kc = 0; kc < 4; ++kc) a[kc] = *(const f16x8*)(abase + kc * 512);

    float wp[16];
    #pragma unroll
    for (int i = 0; i < 16; ++i) wp[i] = 0.f;
    __syncthreads();   // lz ready

    #pragma unroll
    for (int g = 0; g < 8; ++g) {
        const int qtile = tcg * 8 + g;
        const float bias = lz_s[g * 32 + lo];
        const f16* bbase = qf + ((size_t)b * 64 + qtile) * 2048 + l * 8;
        f32x16 c;
        #pragma unroll
        for (int i = 0; i < 16; ++i) c[i] = bias;
        #pragma unroll
        for (int kc = 0; kc < 4; ++kc) {
            const f16x8 bf = *(const f16x8*)(bbase + kc * 512);
            c = __builtin_amdgcn_mfma_f32_32x32x16_f16(a[kc], bf, c, 0, 0, 0);
        }
        #pragma unroll
        for (int i = 0; i < 16; ++i) wp[i] += fexp2(c[i]);
    }
    #pragma unroll
    for (int i = 0; i < 16; ++i) {
        const int row = wv * 32 + (i & 3) + 8 * (i >> 2) + 4 * hi;
        const int col = (lo & 3) | ((((lo >> 2) ^ row) & 7) << 2);
        red[row * 32 + col] = wp[i];
    }
    __syncthreads();
    if (tid < 128 && sIdx * 128 + tid < Nv) {
        float s = 0.f;
        #pragma unroll
        for (int c = 0; c < 8; ++c) {
            const float4 v = *(const float4*)(red + tid * 32 + (((c ^ tid) & 7) << 2));
            s += v.x + v.y + v.z + v.w;
        }
        wpart[(size_t)(b * NCH + tcg) * T_ + sIdx * 128 + tid] = s;
    }
}

// Kernel Y: per 32-row chunk: w[s] = mask ? sum_ck wpart[ck][inv[s]]/T : 0;
//   ypart[b][ch][d] = sum_s w[s]*x[b,s,d] (masked s skipped -> no load);
//   swp[b][ch] = sum_s w[s]
__global__ __launch_bounds__(256, 4) void kY(
    const float* __restrict__ x, const float* __restrict__ wpart,
    const int* __restrict__ mask, const int* __restrict__ inv,
    float* __restrict__ ypart, float* __restrict__ swp)
{
    __shared__ float wloc[32];
    const int b  = blockIdx.y;
    const int ch = blockIdx.x;
    const int tid = threadIdx.x;

    if (tid < 32) {
        const int s = ch * 32 + tid;
        float v = 0.f;
        if (mask[b * T_ + s]) {           // masked lanes never read wpart/inv
            const int j = inv[b * T_ + s];
            const float* wb = wpart + (size_t)(b * NCH) * T_ + j;
            #pragma unroll
            for (int ck = 0; ck < NCH; ++ck) v += wb[(size_t)ck * T_];
            v *= (1.f / (float)T_);
        }
        wloc[tid] = v;
        float sv = v;
        #pragma unroll
        for (int off = 1; off <= 16; off <<= 1) sv += __shfl_xor(sv, off);
        if (tid == 0) swp[b * 64 + ch] = sv;
    }
    __syncthreads();
    const float* xb = x + ((size_t)b * T_ + ch * 32) * D_;
    float acc = 0.f;
    for (int s = 0; s < 32; ++s) {
        const float w = wloc[s];          // uniform across block
        if (w != 0.f) acc += w * xb[(size_t)s * D_ + tid];
    }
    ypart[((size_t)b * 64 + ch) * D_ + tid] = acc;
}

// Kernel OUT: out[b][e] = sum_d y[b,d]*Wv[e,d] + bv[e]*sum_s w[b,s]
__global__ __launch_bounds__(256, 4) void kOUT(
    const float* __restrict__ ypart, const float* __restrict__ swp,
    const float* __restrict__ Wv, const float* __restrict__ bv,
    float* __restrict__ out)
{
    __shared__ __align__(16) float ys[D_];
    __shared__ float sw0;
    const int b   = blockIdx.x;
    const int tid = threadIdx.x;

    float yv = 0.f;
    #pragma unroll
    for (int ch = 0; ch < 64; ++ch) yv += ypart[((size_t)b * 64 + ch) * D_ + tid];
    ys[tid] = yv;
    float s = (tid < 64) ? swp[b * 64 + tid] : 0.f;
    #pragma unroll
    for (int off = 1; off <= 32; off <<= 1) s += __shfl_xor(s, off);
    if (tid == 0) sw0 = s;
    __syncthreads();
    const float sw = sw0;
    const float4* wv4 = (const float4*)(Wv + (size_t)tid * D_);
    const float4* ys4 = (const float4*)ys;
    float o = 0.f;
    #pragma unroll
    for (int i = 0; i < D_ / 4; ++i) {
        const float4 a = wv4[i];
        const float4 y = ys4[i];
        o += a.x * y.x + a.y * y.y + a.z * y.z + a.w * y.w;
    }
    out[(size_t)b * D_ + tid] = o + bv[tid] * sw;
}

// ---------------------------------------------------------------------------
extern "C" void kernel_launch(void* const* d_in, const int* in_sizes, int n_in,
                              void* d_out, int out_size, void* d_ws, size_t ws_size,
                              hipStream_t stream)
{
    const float* x    = (const float*)d_in[0];
    const float* sl   = (const float*)d_in[1];
    const int*   mask = (const int*)d_in[2];
    const float* Wq   = (const float*)d_in[3];
    const float* bq   = (const float*)d_in[4];
    const float* Wk   = (const float*)d_in[5];
    const float* bk   = (const float*)d_in[6];
    const float* Wv   = (const float*)d_in[7];
    const float* bv   = (const float*)d_in[8];
    float* out = (float*)d_out;

    // ws: qf 4 | kf 4 | kfc 4 | zpart 1 | wpart 1 | yp 1 (MB)
    //     | sidx 128K | inv 128K | nv | swp
    f16*   qf    = (f16*)d_ws;
    f16*   kf    = qf  + (size_t)B_ * T_ * QK_;
    f16*   kfc   = kf  + (size_t)B_ * T_ * QK_;
    float* zpart = (float*)(kfc + (size_t)B_ * T_ * QK_);
    float* wpart = zpart + (size_t)B_ * NCH * T_;
    float* yp    = wpart + (size_t)B_ * NCH * T_;
    int*   sidx  = (int*)(yp + (size_t)B_ * 64 * D_);
    int*   inv   = sidx + (size_t)B_ * T_;
    int*   nv    = inv + (size_t)B_ * T_;
    float* swp   = (float*)(nv + 64);

    kP  <<<dim3(64, B_), 256, 0, stream>>>(x, sl, mask, Wq, bq, Wk, bk, qf, kf, sidx, inv, nv);
    kG  <<<dim3(64, B_), 256, 0, stream>>>(kf, sidx, nv, kfc);
    kZ  <<<dim3(128, B_), 256, 0, stream>>>(qf, kfc, nv, zpart);
    kW  <<<dim3(128, B_), 256, 0, stream>>>(qf, kfc, nv, zpart, wpart);
    kY  <<<dim3(64, B_), 256, 0, stream>>>(x, wpart, mask, inv, yp, swp);
    kOUT<<<dim3(B_), 256, 0, stream>>>(yp, swp, Wv, bv, out);
}